// Round 10
// baseline (450.579 us; speedup 1.0000x reference)
//
#include <hip/hip_runtime.h>

// Seq2seq LSTM, round 10: r5 base (verified PASS, 289us) with G_lds round-trip
// replaced by in-register 4x4 quad transpose (shfl_xor) + per-lane cellup.
// 512 blocks x BR=8 rows, 512 threads. Gates interleaved n=4*j+gate (r5 prep,
// byte-identical): the 4 gates of cell (row, j) sit in 4 adjacent lanes of the
// same wave -> quad transpose puts them in one lane -> nonlinearity in regs,
// no G_lds, no gate LDS traffic. Barrier discipline identical to r5:
// B1 -> af reads + MFMA + transpose + cellup -> B2 -> h/x stores -> B1.
//   i,f,o gates scaled by -log2e -> sigmoid = rcp(1 + exp2(g))
//   g gate scaled by +2*log2e   -> tanh    = 1 - 2*rcp(1 + exp2(g))

#define NTHREADS 512
#define NBLOCKS  512
#define BR       8

typedef __attribute__((ext_vector_type(8))) short short8;
typedef __attribute__((ext_vector_type(4))) float f32x4;

#define FRAG_ELEMS 51200
#define BIAS_BYTE_OFF 204800
#define L2E 1.4426950408889634f

__device__ __forceinline__ unsigned short f2bf(float f) {
    unsigned int u = __float_as_uint(f);
    return (unsigned short)((u + 0x7fff + ((u >> 16) & 1)) >> 16);   // RNE
}
__device__ __forceinline__ float bf2f(unsigned short s) {
    return __uint_as_float(((unsigned int)s) << 16);
}
__device__ __forceinline__ float ex2(float x) {
    float r; asm("v_exp_f32 %0, %1" : "=v"(r) : "v"(x)); return r;
}
__device__ __forceinline__ float rcpf_(float x) { return __builtin_amdgcn_rcpf(x); }

// 4x4 transpose within lane quads (verified mapping: out slot g on lane p
// = in reg p of lane (quadbase+g)), then LSTM cell update on (i,f,g,o).
__device__ __forceinline__ float trans_cell(f32x4 v, float& c, int wl) {
    float s0 = __shfl_xor(v[0], 1), s1 = __shfl_xor(v[1], 1);
    float s2 = __shfl_xor(v[2], 1), s3 = __shfl_xor(v[3], 1);
    const bool o1 = (wl & 1) != 0;
    float a0 = o1 ? s1 : v[0];
    float a1 = o1 ? v[1] : s0;
    float a2 = o1 ? s3 : v[2];
    float a3 = o1 ? v[3] : s2;
    float u0 = __shfl_xor(a0, 2), u1 = __shfl_xor(a1, 2);
    float u2 = __shfl_xor(a2, 2), u3 = __shfl_xor(a3, 2);
    const bool o2 = (wl & 2) != 0;
    float gi = o2 ? u2 : a0;
    float gf = o2 ? u3 : a1;
    float gg = o2 ? a2 : u0;
    float go = o2 ? a3 : u1;
    float si = rcpf_(1.f + ex2(gi));
    float sf = rcpf_(1.f + ex2(gf));
    float tg = fmaf(-2.f, rcpf_(1.f + ex2(gg)), 1.f);
    float so = rcpf_(1.f + ex2(go));
    c = fmaf(sf, c, si * tg);
    float tc = fmaf(-2.f, rcpf_(1.f + ex2(c * (2.f * L2E))), 1.f);
    return so * tc;
}

// frag[((t*4+s)*64 + lane)*8 + e] = scale(gate) * WT'[k][n], bf16
// k = s*32+(lane>>4)*8+e, n = t*16+(lane&15), n = 4*jcol + gate  (r5-identical)
__global__ void prep_kernel(const float* __restrict__ Wih_e, const float* __restrict__ Whh_e,
                            const float* __restrict__ bih_e, const float* __restrict__ bhh_e,
                            const float* __restrict__ Wih_d, const float* __restrict__ Whh_d,
                            const float* __restrict__ bih_d, const float* __restrict__ bhh_d,
                            void* __restrict__ ws)
{
    unsigned short* frag = (unsigned short*)ws;
    float* bias = (float*)((char*)ws + BIAS_BYTE_OFF);
    int gid = blockIdx.x * blockDim.x + threadIdx.x;
    int gsz = gridDim.x * blockDim.x;
    for (int i = gid; i < 2 * FRAG_ELEMS; i += gsz) {
        int which = i / FRAG_ELEMS;
        int e = i - which * FRAG_ELEMS;
        int j8 = e & 7, lane = (e >> 3) & 63, s = (e >> 9) & 3, t = e >> 11;
        int k = s * 32 + (lane >> 4) * 8 + j8;
        int n = t * 16 + (lane & 15);
        int jcol = n >> 2, gate = n & 3, col = gate * 100 + jcol;
        float scale = (gate == 2) ? (2.f * L2E) : -L2E;
        const float* Whh = which ? Whh_d : Whh_e;
        const float* Wih = which ? Wih_d : Wih_e;
        float v = 0.f;
        if (k < 100)      v = Whh[col * 100 + k];
        else if (k < 104) v = Wih[col * 4 + (k - 100)];
        frag[i] = f2bf(v * scale);
    }
    for (int i = gid; i < 800; i += gsz) {
        int which = i / 400, n = i - which * 400;
        int jcol = n >> 2, gate = n & 3, col = gate * 100 + jcol;
        float scale = (gate == 2) ? (2.f * L2E) : -L2E;
        bias[i] = scale * (which ? (bih_d[col] + bhh_d[col]) : (bih_e[col] + bhh_e[col]));
    }
}

__global__ __launch_bounds__(NTHREADS)
__attribute__((amdgpu_waves_per_eu(4, 4)))
void seq2seq_kernel(
    const float* __restrict__ inputs,   // [200][4096][4]
    const void* __restrict__ ws,
    const float* __restrict__ Wy,       // [4][100]
    const float* __restrict__ by_g,     // [4]
    float* __restrict__ out)            // [30][4096][4]
{
    // A fragment order: elem = ((k>>3)*16 + row)*8 + (k&7); rows 8..15 stay 0
    __shared__ unsigned short A_frag[2048];      // 4 KB
    __shared__ float Wy_lds[404];                // Wy + by

    const unsigned short* fragE = (const unsigned short*)ws;
    const unsigned short* fragD = fragE + FRAG_ELEMS;
    const float* biasE = (const float*)((const char*)ws + BIAS_BYTE_OFF);
    const float* biasD = biasE + 400;

    const int tid = threadIdx.x;
    const int wid = tid >> 6;          // wave 0..7
    const int wl  = tid & 63;
    const int m   = wl & 15;           // A row / C col
    const int q   = wl >> 4;
    const int blk = blockIdx.x;

    // cell owned by this lane after quad transpose (per tile t): row, col=4t+ca
    const int crow = q * 4 + (wl & 3);
    const int ca   = (wl >> 2) & 3;
    const bool hw  = (q < 2);          // rows 0..7 valid (BR=8)

    for (int i = tid; i < 2048; i += NTHREADS) A_frag[i] = 0;

    // x writers: tid 480..511 -> (row 0..7, comp 0..3)  (r5-identical)
    const bool isx = (tid >= 480);
    const int xu = tid - 480, xr = xu >> 2, xc = xu & 3;
    const float* xsrc = inputs + ((size_t)blk * BR + xr) * 4 + xc;
    const int xelem = (192 + xr) * 8 + 4 + xc;   // k = 100+xc, row xr

    // weights: 3 tiles per wave (t = wid+8i) + tile 24 on wave 7  (r5-identical)
    short8 bfr[3][4]; float breg[3];
    short8 bfr24[4];  float breg24 = 0.f;
    #pragma unroll
    for (int i = 0; i < 3; ++i) {
        int t = wid + 8 * i;
        #pragma unroll
        for (int s = 0; s < 4; ++s)
            bfr[i][s] = *(const short8*)&fragE[((t * 4 + s) * 64 + wl) * 8];
        breg[i] = biasE[t * 16 + m];
    }
    if (wid == 7) {
        #pragma unroll
        for (int s = 0; s < 4; ++s)
            bfr24[s] = *(const short8*)&fragE[((24 * 4 + s) * 64 + wl) * 8];
        breg24 = biasE[24 * 16 + m];
    }

    float cst[3] = {0.f, 0.f, 0.f};
    float cst24 = 0.f;

    float xreg = isx ? xsrc[0] : 0.f;            // x_0
    __syncthreads();                             // A zero-init done
    if (isx) {
        A_frag[xelem] = f2bf(xreg);
        xreg = xsrc[16384];                      // x_1
    }

    // ---------------- encoder: 200 steps ----------------
    for (int step = 0; step < 200; ++step) {
        __syncthreads();                         // B1: A (h,x) ready
        short8 af[4];
        #pragma unroll
        for (int s = 0; s < 4; ++s)
            af[s] = *(const short8*)&A_frag[(s * 64 + wl) * 8];
        float hreg[3], hreg24 = 0.f;
        #pragma unroll
        for (int i = 0; i < 3; ++i) {
            f32x4 acc = {breg[i], breg[i], breg[i], breg[i]};
            #pragma unroll
            for (int s = 0; s < 4; ++s)
                acc = __builtin_amdgcn_mfma_f32_16x16x32_bf16(af[s], bfr[i][s], acc, 0, 0, 0);
            hreg[i] = trans_cell(acc, cst[i], wl);
        }
        if (wid == 7) {
            f32x4 acc = {breg24, breg24, breg24, breg24};
            #pragma unroll
            for (int s = 0; s < 4; ++s)
                acc = __builtin_amdgcn_mfma_f32_16x16x32_bf16(af[s], bfr24[s], acc, 0, 0, 0);
            hreg24 = trans_cell(acc, cst24, wl);
        }
        __syncthreads();                         // B2: all af reads done
        if (hw) {
            #pragma unroll
            for (int i = 0; i < 3; ++i) {
                int col = 4 * (wid + 8 * i) + ca;
                A_frag[((col >> 3) * 16 + crow) * 8 + (col & 7)] = f2bf(hreg[i]);
            }
            if (wid == 7) {
                int col = 96 + ca;
                A_frag[((col >> 3) * 16 + crow) * 8 + (col & 7)] = f2bf(hreg24);
            }
        }
        if (isx && step < 199) {
            A_frag[xelem] = f2bf(xreg);
            if (step < 198) xreg = xsrc[(size_t)(step + 2) * 16384];
        }
    }

    // ---------------- switch to decoder ----------------
    #pragma unroll
    for (int i = 0; i < 3; ++i) {
        int t = wid + 8 * i;
        #pragma unroll
        for (int s = 0; s < 4; ++s)
            bfr[i][s] = *(const short8*)&fragD[((t * 4 + s) * 64 + wl) * 8];
        breg[i] = biasD[t * 16 + m];
    }
    if (wid == 7) {
        #pragma unroll
        for (int s = 0; s < 4; ++s)
            bfr24[s] = *(const short8*)&fragD[((24 * 4 + s) * 64 + wl) * 8];
        breg24 = biasD[24 * 16 + m];
    }
    cst[0] = cst[1] = cst[2] = 0.f;
    cst24 = 0.f;                                 // c resets; h carries over
    if (isx) A_frag[xelem] = 0;                  // y_prev = 0
    for (int i = tid; i < 404; i += NTHREADS)
        Wy_lds[i] = (i < 400) ? Wy[i] : by_g[i - 400];

    const int yrow = tid >> 5, yln = tid & 31;
    const bool isy = (tid < 256);                // rows 0..7

    // ---------------- decoder: 30 autoregressive steps ----------------
    for (int step = 0; step < 30; ++step) {
        __syncthreads();                         // B1: A ready (+ Wy staged)
        short8 af[4];
        #pragma unroll
        for (int s = 0; s < 4; ++s)
            af[s] = *(const short8*)&A_frag[(s * 64 + wl) * 8];
        float hreg[3], hreg24 = 0.f;
        #pragma unroll
        for (int i = 0; i < 3; ++i) {
            f32x4 acc = {breg[i], breg[i], breg[i], breg[i]};
            #pragma unroll
            for (int s = 0; s < 4; ++s)
                acc = __builtin_amdgcn_mfma_f32_16x16x32_bf16(af[s], bfr[i][s], acc, 0, 0, 0);
            hreg[i] = trans_cell(acc, cst[i], wl);
        }
        if (wid == 7) {
            f32x4 acc = {breg24, breg24, breg24, breg24};
            #pragma unroll
            for (int s = 0; s < 4; ++s)
                acc = __builtin_amdgcn_mfma_f32_16x16x32_bf16(af[s], bfr24[s], acc, 0, 0, 0);
            hreg24 = trans_cell(acc, cst24, wl);
        }
        __syncthreads();                         // B2: af reads done
        if (hw) {
            #pragma unroll
            for (int i = 0; i < 3; ++i) {
                int col = 4 * (wid + 8 * i) + ca;
                A_frag[((col >> 3) * 16 + crow) * 8 + (col & 7)] = f2bf(hreg[i]);
            }
            if (wid == 7) {
                int col = 96 + ca;
                A_frag[((col >> 3) * 16 + crow) * 8 + (col & 7)] = f2bf(hreg24);
            }
        }
        __syncthreads();                         // B3: h complete
        if (isy) {
            float p0 = 0.f, p1 = 0.f, p2 = 0.f, p3 = 0.f;
            #pragma unroll
            for (int i = 0; i < 4; ++i) {
                int jj = yln + 32 * i;
                if (jj < 100) {
                    float hv = bf2f(A_frag[((jj >> 3) * 16 + yrow) * 8 + (jj & 7)]);
                    p0 = fmaf(Wy_lds[0 * 100 + jj], hv, p0);
                    p1 = fmaf(Wy_lds[1 * 100 + jj], hv, p1);
                    p2 = fmaf(Wy_lds[2 * 100 + jj], hv, p2);
                    p3 = fmaf(Wy_lds[3 * 100 + jj], hv, p3);
                }
            }
            #pragma unroll
            for (int mm = 16; mm >= 1; mm >>= 1) {
                p0 += __shfl_xor(p0, mm, 32);
                p1 += __shfl_xor(p1, mm, 32);
                p2 += __shfl_xor(p2, mm, 32);
                p3 += __shfl_xor(p3, mm, 32);
            }
            if (yln == 0) {
                float y0 = p0 + Wy_lds[400], y1 = p1 + Wy_lds[401];
                float y2 = p2 + Wy_lds[402], y3 = p3 + Wy_lds[403];
                *(float4*)&out[((size_t)step * 4096 + blk * BR + yrow) * 4] =
                    make_float4(y0, y1, y2, y3);
                A_frag[(192 + yrow) * 8 + 4] = f2bf(y0);   // y feedback
                A_frag[(192 + yrow) * 8 + 5] = f2bf(y1);
                A_frag[(192 + yrow) * 8 + 6] = f2bf(y2);
                A_frag[(192 + yrow) * 8 + 7] = f2bf(y3);
            }
        }
    }
}

extern "C" void kernel_launch(void* const* d_in, const int* in_sizes, int n_in,
                              void* d_out, int out_size, void* d_ws, size_t ws_size,
                              hipStream_t stream)
{
    (void)in_sizes; (void)n_in; (void)out_size; (void)ws_size;
    const float* inputs = (const float*)d_in[0];
    const float* Wih_e  = (const float*)d_in[1];
    const float* Whh_e  = (const float*)d_in[2];
    const float* bih_e  = (const float*)d_in[3];
    const float* bhh_e  = (const float*)d_in[4];
    const float* Wih_d  = (const float*)d_in[5];
    const float* Whh_d  = (const float*)d_in[6];
    const float* bih_d  = (const float*)d_in[7];
    const float* bhh_d  = (const float*)d_in[8];
    const float* Wy     = (const float*)d_in[9];
    const float* by     = (const float*)d_in[10];
    float* out = (float*)d_out;

    hipLaunchKernelGGL(prep_kernel, dim3(256), dim3(256), 0, stream,
                       Wih_e, Whh_e, bih_e, bhh_e, Wih_d, Whh_d, bih_d, bhh_d, d_ws);
    hipLaunchKernelGGL(seq2seq_kernel, dim3(NBLOCKS), dim3(NTHREADS), 0, stream,
                       inputs, d_ws, Wy, by, out);
}

// Round 12
// 257.589 us; speedup vs baseline: 1.7492x; 1.7492x over previous
//
#include <hip/hip_runtime.h>

// Seq2seq LSTM, round 12: r5 base (verified PASS, 289us) + LDS x-staging.
// SINGLE DELTA vs r5: the per-step global x-prefetch (whose in-flight load
// forced a vmcnt(0) drain at every __syncthreads -> ~500-900 cyc barrier
// stall per step for ALL waves) is replaced by a one-time bulk stage of the
// block's input slice [200][8][4] into LDS (bf16, 12.8 KB). Encoder steps do
// zero global memory ops. Everything else identical to r5:
//   i,f,o gates scaled by -log2e -> sigmoid = rcp(1 + exp2(g))
//   g gate scaled by +2*log2e   -> tanh    = 1 - 2*rcp(1 + exp2(g))

#define NTHREADS 512
#define NBLOCKS  512
#define BR       8

typedef __attribute__((ext_vector_type(8))) short short8;
typedef __attribute__((ext_vector_type(4))) float f32x4;

#define FRAG_ELEMS 51200
#define BIAS_BYTE_OFF 204800
#define L2E 1.4426950408889634f

__device__ __forceinline__ unsigned short f2bf(float f) {
    unsigned int u = __float_as_uint(f);
    return (unsigned short)((u + 0x7fff + ((u >> 16) & 1)) >> 16);   // RNE
}
__device__ __forceinline__ float bf2f(unsigned short s) {
    return __uint_as_float(((unsigned int)s) << 16);
}
__device__ __forceinline__ float ex2(float x) {
    float r; asm("v_exp_f32 %0, %1" : "=v"(r) : "v"(x)); return r;
}
__device__ __forceinline__ float rcpf_(float x) { return __builtin_amdgcn_rcpf(x); }

// h = cell(g, c) with pre-scaled gates
__device__ __forceinline__ float cellup(const f32x4 g, float& c) {
    float si = rcpf_(1.f + ex2(g[0]));
    float sf = rcpf_(1.f + ex2(g[1]));
    float tg = fmaf(-2.f, rcpf_(1.f + ex2(g[2])), 1.f);
    float so = rcpf_(1.f + ex2(g[3]));
    c = fmaf(sf, c, si * tg);
    float tc = fmaf(-2.f, rcpf_(1.f + ex2(c * (2.f * L2E))), 1.f);
    return so * tc;
}

// frag[((t*4+s)*64 + lane)*8 + e] = scale(gate) * WT'[k][n], bf16
// k = s*32+(lane>>4)*8+e, n = t*16+(lane&15), n = 4*jcol + gate  (r5-identical)
__global__ void prep_kernel(const float* __restrict__ Wih_e, const float* __restrict__ Whh_e,
                            const float* __restrict__ bih_e, const float* __restrict__ bhh_e,
                            const float* __restrict__ Wih_d, const float* __restrict__ Whh_d,
                            const float* __restrict__ bih_d, const float* __restrict__ bhh_d,
                            void* __restrict__ ws)
{
    unsigned short* frag = (unsigned short*)ws;
    float* bias = (float*)((char*)ws + BIAS_BYTE_OFF);
    int gid = blockIdx.x * blockDim.x + threadIdx.x;
    int gsz = gridDim.x * blockDim.x;
    for (int i = gid; i < 2 * FRAG_ELEMS; i += gsz) {
        int which = i / FRAG_ELEMS;
        int e = i - which * FRAG_ELEMS;
        int j8 = e & 7, lane = (e >> 3) & 63, s = (e >> 9) & 3, t = e >> 11;
        int k = s * 32 + (lane >> 4) * 8 + j8;
        int n = t * 16 + (lane & 15);
        int jcol = n >> 2, gate = n & 3, col = gate * 100 + jcol;
        float scale = (gate == 2) ? (2.f * L2E) : -L2E;
        const float* Whh = which ? Whh_d : Whh_e;
        const float* Wih = which ? Wih_d : Wih_e;
        float v = 0.f;
        if (k < 100)      v = Whh[col * 100 + k];
        else if (k < 104) v = Wih[col * 4 + (k - 100)];
        frag[i] = f2bf(v * scale);
    }
    for (int i = gid; i < 800; i += gsz) {
        int which = i / 400, n = i - which * 400;
        int jcol = n >> 2, gate = n & 3, col = gate * 100 + jcol;
        float scale = (gate == 2) ? (2.f * L2E) : -L2E;
        bias[i] = scale * (which ? (bih_d[col] + bhh_d[col]) : (bih_e[col] + bhh_e[col]));
    }
}

__global__ __launch_bounds__(NTHREADS)
__attribute__((amdgpu_waves_per_eu(4, 4)))
void seq2seq_kernel(
    const float* __restrict__ inputs,   // [200][4096][4]
    const void* __restrict__ ws,
    const float* __restrict__ Wy,       // [4][100]
    const float* __restrict__ by_g,     // [4]
    float* __restrict__ out)            // [30][4096][4]
{
    // A fragment order: elem = ((k>>3)*16 + row)*8 + (k&7); rows 8..15 stay 0
    __shared__ unsigned short A_frag[2048];      // 4 KB
    __shared__ float G_lds[BR * 404];            // 12.9 KB
    __shared__ float Wy_lds[404];                // Wy + by
    __shared__ unsigned short xstage[6400];      // 12.8 KB: x[200][8][4] bf16

    const unsigned short* fragE = (const unsigned short*)ws;
    const unsigned short* fragD = fragE + FRAG_ELEMS;
    const float* biasE = (const float*)((const char*)ws + BIAS_BYTE_OFF);
    const float* biasD = biasE + 400;

    const int tid = threadIdx.x;
    const int wid = tid >> 6;          // wave 0..7
    const int wl  = tid & 63;
    const int m   = wl & 15;           // A row / C col
    const int q   = wl >> 4;
    const int blk = blockIdx.x;

    for (int i = tid; i < 2048; i += NTHREADS) A_frag[i] = 0;

    // one-time bulk x staging: xstage[s*32 + xr*4 + xc] = bf16(x[s][row][c])
    for (int i = tid; i < 6400; i += NTHREADS) {
        int s = i >> 5, u = i & 31;
        xstage[i] = f2bf(inputs[((size_t)s * 4096 + blk * BR + (u >> 2)) * 4 + (u & 3)]);
    }

    // cell-update mapping: threads 0..399 own cells (r, 2*jp) and (r, 2*jp+1)
    const int cr = tid & 7, jp = tid >> 3;
    const int j0 = 2 * jp;
    const bool isc = (tid < 400);
    float cst[2] = {0.f, 0.f};

    // x writers: tid 480..511 (wave 7 upper half)
    const bool isx = (tid >= 480);
    const int xu = tid - 480;
    const int xr = xu >> 2, xc = xu & 3;
    const int xelem = (192 + xr) * 8 + 4 + xc;   // k = 100+xc, row xr

    // weights: 3 tiles per wave (t = wid+8i, i<3) + tile 24 on wave 7
    short8 bfr[3][4]; float breg[3];
    short8 bfr24[4];  float breg24 = 0.f;
    #pragma unroll
    for (int i = 0; i < 3; ++i) {
        int t = wid + 8 * i;
        #pragma unroll
        for (int s = 0; s < 4; ++s)
            bfr[i][s] = *(const short8*)&fragE[((t * 4 + s) * 64 + wl) * 8];
        breg[i] = biasE[t * 16 + m];
    }
    if (wid == 7) {
        #pragma unroll
        for (int s = 0; s < 4; ++s)
            bfr24[s] = *(const short8*)&fragE[((24 * 4 + s) * 64 + wl) * 8];
        breg24 = biasE[24 * 16 + m];
    }

    __syncthreads();                             // A zero-init + xstage done
    if (isx) A_frag[xelem] = xstage[xu];         // x(0)

    // ---------------- encoder: 200 steps ----------------
    for (int step = 0; step < 200; ++step) {
        __syncthreads();                         // B1: A (h,x) ready
        short8 af[4];
        #pragma unroll
        for (int s = 0; s < 4; ++s)
            af[s] = *(const short8*)&A_frag[(s * 64 + wl) * 8];
        #pragma unroll
        for (int i = 0; i < 3; ++i) {
            int t = wid + 8 * i;
            f32x4 acc = {breg[i], breg[i], breg[i], breg[i]};
            #pragma unroll
            for (int s = 0; s < 4; ++s)
                acc = __builtin_amdgcn_mfma_f32_16x16x32_bf16(af[s], bfr[i][s], acc, 0, 0, 0);
            if (q < 2) {
                #pragma unroll
                for (int r = 0; r < 4; ++r)
                    G_lds[(q * 4 + r) * 404 + t * 16 + m] = acc[r];
            }
        }
        if (wid == 7) {
            f32x4 acc = {breg24, breg24, breg24, breg24};
            #pragma unroll
            for (int s = 0; s < 4; ++s)
                acc = __builtin_amdgcn_mfma_f32_16x16x32_bf16(af[s], bfr24[s], acc, 0, 0, 0);
            if (q < 2) {
                #pragma unroll
                for (int r = 0; r < 4; ++r)
                    G_lds[(q * 4 + r) * 404 + 24 * 16 + m] = acc[r];
            }
        }
        __syncthreads();                         // B2: G ready, af reads done
        if (isc) {
            f32x4 ga = *(const f32x4*)&G_lds[cr * 404 + 8 * jp];
            f32x4 gb = *(const f32x4*)&G_lds[cr * 404 + 8 * jp + 4];
            float h0 = cellup(ga, cst[0]);
            float h1 = cellup(gb, cst[1]);
            unsigned int pk;
            asm("v_cvt_pk_bf16_f32 %0, %1, %2" : "=v"(pk) : "v"(h0), "v"(h1));
            *(unsigned int*)&A_frag[((j0 >> 3) * 16 + cr) * 8 + (j0 & 7)] = pk;
        }
        if (isx && step < 199)
            A_frag[xelem] = xstage[(step + 1) * 32 + xu];   // x(s+1), LDS->LDS
    }

    // ---------------- switch to decoder ----------------
    #pragma unroll
    for (int i = 0; i < 3; ++i) {
        int t = wid + 8 * i;
        #pragma unroll
        for (int s = 0; s < 4; ++s)
            bfr[i][s] = *(const short8*)&fragD[((t * 4 + s) * 64 + wl) * 8];
        breg[i] = biasD[t * 16 + m];
    }
    if (wid == 7) {
        #pragma unroll
        for (int s = 0; s < 4; ++s)
            bfr24[s] = *(const short8*)&fragD[((24 * 4 + s) * 64 + wl) * 8];
        breg24 = biasD[24 * 16 + m];
    }
    cst[0] = cst[1] = 0.f;                       // c resets; h carries over
    if (isx) A_frag[xelem] = 0;                  // y_prev = 0
    for (int i = tid; i < 404; i += NTHREADS)
        Wy_lds[i] = (i < 400) ? Wy[i] : by_g[i - 400];

    const int yrow = tid >> 5, yln = tid & 31;
    const bool isy = (tid < 256);

    // ---------------- decoder: 30 autoregressive steps ----------------
    for (int step = 0; step < 30; ++step) {
        __syncthreads();                         // B1: A ready (+ Wy staged)
        short8 af[4];
        #pragma unroll
        for (int s = 0; s < 4; ++s)
            af[s] = *(const short8*)&A_frag[(s * 64 + wl) * 8];
        #pragma unroll
        for (int i = 0; i < 3; ++i) {
            int t = wid + 8 * i;
            f32x4 acc = {breg[i], breg[i], breg[i], breg[i]};
            #pragma unroll
            for (int s = 0; s < 4; ++s)
                acc = __builtin_amdgcn_mfma_f32_16x16x32_bf16(af[s], bfr[i][s], acc, 0, 0, 0);
            if (q < 2) {
                #pragma unroll
                for (int r = 0; r < 4; ++r)
                    G_lds[(q * 4 + r) * 404 + t * 16 + m] = acc[r];
            }
        }
        if (wid == 7) {
            f32x4 acc = {breg24, breg24, breg24, breg24};
            #pragma unroll
            for (int s = 0; s < 4; ++s)
                acc = __builtin_amdgcn_mfma_f32_16x16x32_bf16(af[s], bfr24[s], acc, 0, 0, 0);
            if (q < 2) {
                #pragma unroll
                for (int r = 0; r < 4; ++r)
                    G_lds[(q * 4 + r) * 404 + 24 * 16 + m] = acc[r];
            }
        }
        __syncthreads();                         // B2: G ready
        if (isc) {
            f32x4 ga = *(const f32x4*)&G_lds[cr * 404 + 8 * jp];
            f32x4 gb = *(const f32x4*)&G_lds[cr * 404 + 8 * jp + 4];
            float h0 = cellup(ga, cst[0]);
            float h1 = cellup(gb, cst[1]);
            unsigned int pk;
            asm("v_cvt_pk_bf16_f32 %0, %1, %2" : "=v"(pk) : "v"(h0), "v"(h1));
            *(unsigned int*)&A_frag[((j0 >> 3) * 16 + cr) * 8 + (j0 & 7)] = pk;
        }
        __syncthreads();                         // B3: h complete
        if (isy) {
            float p0 = 0.f, p1 = 0.f, p2 = 0.f, p3 = 0.f;
            #pragma unroll
            for (int i = 0; i < 4; ++i) {
                int j = yln + 32 * i;
                if (j < 100) {
                    float hv = bf2f(A_frag[((j >> 3) * 16 + yrow) * 8 + (j & 7)]);
                    p0 = fmaf(Wy_lds[0 * 100 + j], hv, p0);
                    p1 = fmaf(Wy_lds[1 * 100 + j], hv, p1);
                    p2 = fmaf(Wy_lds[2 * 100 + j], hv, p2);
                    p3 = fmaf(Wy_lds[3 * 100 + j], hv, p3);
                }
            }
            #pragma unroll
            for (int mm = 16; mm >= 1; mm >>= 1) {
                p0 += __shfl_xor(p0, mm, 32);
                p1 += __shfl_xor(p1, mm, 32);
                p2 += __shfl_xor(p2, mm, 32);
                p3 += __shfl_xor(p3, mm, 32);
            }
            if (yln == 0) {
                float y0 = p0 + Wy_lds[400], y1 = p1 + Wy_lds[401];
                float y2 = p2 + Wy_lds[402], y3 = p3 + Wy_lds[403];
                float4 yv = make_float4(y0, y1, y2, y3);
                *(float4*)&out[((size_t)step * 4096 + blk * BR + yrow) * 4] = yv;
                unsigned int pk01, pk23;
                asm("v_cvt_pk_bf16_f32 %0, %1, %2" : "=v"(pk01) : "v"(y0), "v"(y1));
                asm("v_cvt_pk_bf16_f32 %0, %1, %2" : "=v"(pk23) : "v"(y2), "v"(y3));
                *(unsigned int*)&A_frag[(192 + yrow) * 8 + 4] = pk01;
                *(unsigned int*)&A_frag[(192 + yrow) * 8 + 6] = pk23;
            }
        }
    }
}

extern "C" void kernel_launch(void* const* d_in, const int* in_sizes, int n_in,
                              void* d_out, int out_size, void* d_ws, size_t ws_size,
                              hipStream_t stream)
{
    (void)in_sizes; (void)n_in; (void)out_size; (void)ws_size;
    const float* inputs = (const float*)d_in[0];
    const float* Wih_e  = (const float*)d_in[1];
    const float* Whh_e  = (const float*)d_in[2];
    const float* bih_e  = (const float*)d_in[3];
    const float* bhh_e  = (const float*)d_in[4];
    const float* Wih_d  = (const float*)d_in[5];
    const float* Whh_d  = (const float*)d_in[6];
    const float* bih_d  = (const float*)d_in[7];
    const float* bhh_d  = (const float*)d_in[8];
    const float* Wy     = (const float*)d_in[9];
    const float* by     = (const float*)d_in[10];
    float* out = (float*)d_out;

    hipLaunchKernelGGL(prep_kernel, dim3(256), dim3(256), 0, stream,
                       Wih_e, Whh_e, bih_e, bhh_e, Wih_d, Whh_d, bih_d, bhh_d, d_ws);
    hipLaunchKernelGGL(seq2seq_kernel, dim3(NBLOCKS), dim3(NTHREADS), 0, stream,
                       inputs, d_ws, Wy, by, out);
}